// Round 15
// baseline (284.839 us; speedup 1.0000x reference)
//
#include <hip/hip_runtime.h>
#include <hip/hip_bf16.h>

#define B_ 4096
#define N_ 30
#define D_ 512
#define H_ 4
#define M_ (B_*N_)      // 122880 tokens
#define PE_ROWS 31

typedef unsigned short u16;
typedef __attribute__((ext_vector_type(8))) short bf16x8;
typedef __attribute__((ext_vector_type(4))) float f32x4;

__device__ __forceinline__ float bf2f(u16 s) { return __uint_as_float(((unsigned)s) << 16); }
__device__ __forceinline__ u16 f2bf(float f) {
  __hip_bfloat16 h = __float2bfloat16(f);
  return *reinterpret_cast<u16*>(&h);
}

// fast tanh: 1 - 2/(exp(2x)+1)
__device__ __forceinline__ float ftanh(float x) {
  float e = __expf(2.f * x);
  return 1.f - 2.f * __builtin_amdgcn_rcpf(e + 1.f);
}

// async global->LDS, 16B per lane. LDS dest = wave-uniform base + lane*16.
__device__ __forceinline__ void gll16(const void* g, void* l) {
  __builtin_amdgcn_global_load_lds(
      (const __attribute__((address_space(1))) unsigned int*)g,
      (__attribute__((address_space(3))) unsigned int*)l, 16, 0, 0);
}

// full-wave (64-lane) reductions; interleaved variants run k independent
// trees in ONE 6-round pass (latency ~= single wsum).
__device__ __forceinline__ float wsum(float v) {
  #pragma unroll
  for (int m = 32; m >= 1; m >>= 1) v += __shfl_xor(v, m);
  return v;
}
__device__ __forceinline__ void wsum2(float& a, float& b) {
  #pragma unroll
  for (int m = 32; m >= 1; m >>= 1) {
    a += __shfl_xor(a, m); b += __shfl_xor(b, m);
  }
}
__device__ __forceinline__ void wsum4(float& a, float& b, float& c, float& d) {
  #pragma unroll
  for (int m = 32; m >= 1; m >>= 1) {
    a += __shfl_xor(a, m); b += __shfl_xor(b, m);
    c += __shfl_xor(c, m); d += __shfl_xor(d, m);
  }
}
__device__ __forceinline__ float wmax(float v) {
  #pragma unroll
  for (int m = 32; m >= 1; m >>= 1) v = fmaxf(v, __shfl_xor(v, m));
  return v;
}

// K1 mega: blocks [0,4096) = per-batch prep (paired-token interleaved
// reductions); blocks [4096+) do preamble transposes + peW concurrently.
__global__ __launch_bounds__(512) void k1_mega(
    const float* __restrict__ x, const int* __restrict__ order,
    const float* __restrict__ ndocs, const float* __restrict__ dw,
    const float* __restrict__ pe, const float* __restrict__ g1,
    const float* __restrict__ bln1,
    const float* __restrict__ w1, const float* __restrict__ fw,
    u16* __restrict__ x1bf, u16* __restrict__ mpbf, float* __restrict__ mpx,
    float* __restrict__ cosb,
    u16* __restrict__ w1T, u16* __restrict__ w1mT, u16* __restrict__ fwT,
    float* __restrict__ peW) {
  __shared__ __align__(16) char smem[32896];
  int bid = blockIdx.x;
  int tid = threadIdx.x;
  if (bid >= B_) {
    int r = bid - B_;
    if (r < 384) {
      const float* in; u16* outp; int Kdim, Jdim, bx, by;
      if (r < 64)       { in = w1;            outp = w1T;  Kdim = 512;  Jdim = 512;  bx = r >> 3;        by = r & 7; }
      else if (r < 128) { in = w1 + 512*512;  outp = w1mT; Kdim = 512;  Jdim = 512;  bx = (r-64) >> 3;   by = (r-64) & 7; }
      else              { in = fw;            outp = fwT;  Kdim = 2048; Jdim = 512;  bx = (r-128) >> 3;  by = (r-128) & 7; }
      int k0 = bx*64, j0 = by*64;
      float* tile = (float*)smem;            // [64][65]
      int rowk = tid >> 3, c8 = (tid & 7) * 8;
      float4 v0 = *(const float4*)&in[(size_t)(k0+rowk)*Jdim + j0 + c8];
      float4 v1 = *(const float4*)&in[(size_t)(k0+rowk)*Jdim + j0 + c8 + 4];
      float* tr = tile + rowk*65;
      tr[c8+0]=v0.x; tr[c8+1]=v0.y; tr[c8+2]=v0.z; tr[c8+3]=v0.w;
      tr[c8+4]=v1.x; tr[c8+5]=v1.y; tr[c8+6]=v1.z; tr[c8+7]=v1.w;
      __syncthreads();
      int j = tid >> 3, k8 = (tid & 7) * 8;
      u16 tmp[8];
      #pragma unroll
      for (int i = 0; i < 8; ++i) tmp[i] = f2bf(tile[(k8+i)*65 + j]);
      *(uint4*)&outp[(size_t)(j0+j)*Kdim + k0 + k8] = *(uint4*)tmp;
    } else {
      int p = r - 384;
      float* pes = (float*)smem;
      pes[tid] = pe[(size_t)p*D_ + tid];
      __syncthreads();
      float acc = 0.f;
      for (int dd = 0; dd < D_; ++dd) acc += pes[dd] * w1[(size_t)dd*D_ + tid];
      peW[p*D_ + tid] = acc;
    }
    return;
  }
  // --- k1 path ---
  float* lds_mp  = (float*)smem;
  float* lds_mpx = lds_mp + 8*512;
  float* xps     = lds_mpx + 8*512;
  int b = bid;
  int wid = tid >> 6, lane = tid & 63;
  int d0 = lane * 8;
  float g[8], bl[8];
  *(float4*)&g[0]  = *(const float4*)&g1[d0];
  *(float4*)&g[4]  = *(const float4*)&g1[d0+4];
  *(float4*)&bl[0] = *(const float4*)&bln1[d0];
  *(float4*)&bl[4] = *(const float4*)&bln1[d0+4];
  float xp_reg[4][8];
  float accmp[8] = {0,0,0,0,0,0,0,0}, accmpx[8] = {0,0,0,0,0,0,0,0};
  #pragma unroll
  for (int tp = 0; tp < 2; ++tp) {
    int n0 = wid + 16*tp, n1 = n0 + 8;
    bool a1 = (n1 < N_);                     // wave-uniform
    int tok0 = b*N_ + n0, tok1 = b*N_ + n1;
    float v0[8], v1[8];
    *(float4*)&v0[0] = *(const float4*)&x[(size_t)tok0*D_ + d0];
    *(float4*)&v0[4] = *(const float4*)&x[(size_t)tok0*D_ + d0 + 4];
    int o0 = order[tok0];
    float wv0 = dw[tok0];
    int o1 = 0; float wv1 = 0.f;
    if (a1) {
      *(float4*)&v1[0] = *(const float4*)&x[(size_t)tok1*D_ + d0];
      *(float4*)&v1[4] = *(const float4*)&x[(size_t)tok1*D_ + d0 + 4];
      o1 = order[tok1];
      wv1 = dw[tok1];
    }
    float ss0=0.f, sm0=0.f, ss1=0.f, sm1=0.f;
    #pragma unroll
    for (int i = 0; i < 8; ++i) { ss0 += v0[i]*v0[i]; sm0 += v0[i]; }
    if (a1) {
      #pragma unroll
      for (int i = 0; i < 8; ++i) { ss1 += v1[i]*v1[i]; sm1 += v1[i]; }
    }
    wsum4(ss0, sm0, ss1, sm1);               // 4 chains, one 6-round pass
    // token 0
    float inv0 = 1.f / fmaxf(sqrtf(ss0), 1e-8f);
    float mu0 = sm0 * inv0 * (1.f/D_);
    float rs0 = 1.f / sqrtf(ss0*inv0*inv0*(1.f/D_) - mu0*mu0 + 1e-5f);
    float p80[8];
    *(float4*)&p80[0] = *(const float4*)&pe[(size_t)o0*D_ + d0];
    *(float4*)&p80[4] = *(const float4*)&pe[(size_t)o0*D_ + d0 + 4];
    float sq0 = 0.f, sq1 = 0.f;
    bf16x8 xb0;
    #pragma unroll
    for (int i = 0; i < 8; ++i) {
      float x1v = g[i]*((v0[i]*inv0 - mu0)*rs0) + bl[i];
      xb0[i] = (short)f2bf(x1v);
      float xpv = x1v + p80[i];
      xp_reg[2*tp][i] = xpv;
      accmp[i]  += wv0*xpv;
      accmpx[i] += wv0*x1v;
      sq0 += xpv*xpv;
    }
    *(bf16x8*)&x1bf[(size_t)tok0*D_ + d0] = xb0;
    // token 1 (guarded, wave-uniform)
    if (a1) {
      float inv1 = 1.f / fmaxf(sqrtf(ss1), 1e-8f);
      float mu1 = sm1 * inv1 * (1.f/D_);
      float rs1 = 1.f / sqrtf(ss1*inv1*inv1*(1.f/D_) - mu1*mu1 + 1e-5f);
      float p81[8];
      *(float4*)&p81[0] = *(const float4*)&pe[(size_t)o1*D_ + d0];
      *(float4*)&p81[4] = *(const float4*)&pe[(size_t)o1*D_ + d0 + 4];
      bf16x8 xb1;
      #pragma unroll
      for (int i = 0; i < 8; ++i) {
        float x1v = g[i]*((v1[i]*inv1 - mu1)*rs1) + bl[i];
        xb1[i] = (short)f2bf(x1v);
        float xpv = x1v + p81[i];
        xp_reg[2*tp+1][i] = xpv;
        accmp[i]  += wv1*xpv;
        accmpx[i] += wv1*x1v;
        sq1 += xpv*xpv;
      }
      *(bf16x8*)&x1bf[(size_t)tok1*D_ + d0] = xb1;
    }
    wsum2(sq0, sq1);
    if (lane == 0) {
      xps[n0] = sq0;
      if (a1) xps[n1] = sq1;
    }
  }
  #pragma unroll
  for (int i = 0; i < 8; i += 4) {
    *(float4*)&lds_mp[wid*512 + d0 + i]  = *(float4*)&accmp[i];
    *(float4*)&lds_mpx[wid*512 + d0 + i] = *(float4*)&accmpx[i];
  }
  __syncthreads();
  float invnd = 1.f / ndocs[b];
  float mpv[8] = {0,0,0,0,0,0,0,0}, mpxv[8] = {0,0,0,0,0,0,0,0};
  #pragma unroll
  for (int w = 0; w < 8; ++w) {
    #pragma unroll
    for (int i = 0; i < 8; i += 4) {
      float4 a = *(float4*)&lds_mp[w*512 + d0 + i];
      mpv[i+0] += a.x; mpv[i+1] += a.y; mpv[i+2] += a.z; mpv[i+3] += a.w;
      float4 c = *(float4*)&lds_mpx[w*512 + d0 + i];
      mpxv[i+0] += c.x; mpxv[i+1] += c.y; mpxv[i+2] += c.z; mpxv[i+3] += c.w;
    }
  }
  #pragma unroll
  for (int i = 0; i < 8; ++i) { mpv[i] *= invnd; mpxv[i] *= invnd; }
  if (wid == 0) {
    bf16x8 mb;
    #pragma unroll
    for (int i = 0; i < 8; ++i) mb[i] = (short)f2bf(mpv[i]);
    *(bf16x8*)&mpbf[(size_t)b*D_ + d0] = mb;
  }
  if (wid == 1) {
    #pragma unroll
    for (int i = 0; i < 8; i += 4)
      *(float4*)&mpx[(size_t)b*D_ + d0 + i] = *(float4*)&mpxv[i];
  }
  float mn = 0.f;
  #pragma unroll
  for (int i = 0; i < 8; ++i) mn += mpv[i]*mpv[i];
  float mpn = sqrtf(wsum(mn));
  // phase C: all 4 cosine dots in one interleaved reduce
  float dot[4];
  #pragma unroll
  for (int t = 0; t < 4; ++t) {
    int n = wid + 8*t;
    float dd = 0.f;
    if (n < N_) {
      #pragma unroll
      for (int i = 0; i < 8; ++i) dd += mpv[i]*xp_reg[t][i];
    }
    dot[t] = dd;
  }
  wsum4(dot[0], dot[1], dot[2], dot[3]);
  if (lane == 0) {
    #pragma unroll
    for (int t = 0; t < 4; ++t) {
      int n = wid + 8*t;
      if (n < N_)
        cosb[b*N_ + n] = dot[t] / fmaxf(mpn * sqrtf(xps[n]), 1e-8f);
    }
  }
}

// K2: mpW = mp @ W_mid + b1, MFMA 128x128 tile, BK=64, 128 blocks.
__global__ __launch_bounds__(256, 3) void k2_mpw(
    const u16* __restrict__ mpbf, const u16* __restrict__ w1mT,
    const float* __restrict__ b1, float* __restrict__ mpW) {
  __shared__ __align__(16) u16 As[128*64];
  __shared__ __align__(16) u16 Bs[128*64];
  int tid = threadIdx.x;
  int lane = tid & 63, wid = tid >> 6;
  int wg = (blockIdx.x & 7)*16 + (blockIdx.x >> 3);
  int colb = wg & 3, rowb = wg >> 2;
  int row0 = rowb*128, col0 = colb*128;
  int wm = wid >> 1, wn = wid & 1;
  int lr = lane & 15, lk = lane >> 4;
  int srow = lane >> 3;
  int skel = ((lane & 7) ^ srow) << 3;
  f32x4 acc[4][4];
  #pragma unroll
  for (int nf = 0; nf < 4; ++nf) {
    float bv = b1[col0 + wn*64 + nf*16 + lr];
    #pragma unroll
    for (int mf = 0; mf < 4; ++mf)
      acc[mf][nf] = (f32x4){bv, bv, bv, bv};
  }
  for (int k0 = 0; k0 < D_; k0 += 64) {
    __syncthreads();
    #pragma unroll
    for (int i = 0; i < 4; ++i) {
      int rb = wid*32 + i*8;
      gll16(&mpbf[(size_t)(row0 + rb + srow)*D_ + k0 + skel], &As[rb*64]);
      gll16(&w1mT[(size_t)(col0 + rb + srow)*D_ + k0 + skel], &Bs[rb*64]);
    }
    __syncthreads();
    #pragma unroll
    for (int kk = 0; kk < 2; ++kk) {
      int kb = (kk*64 + lk*16) ^ ((lr & 7) << 4);
      bf16x8 a[4];
      #pragma unroll
      for (int mf = 0; mf < 4; ++mf)
        a[mf] = *(const bf16x8*)((const char*)As + (wm*64 + mf*16 + lr)*128 + kb);
      #pragma unroll
      for (int nf = 0; nf < 4; ++nf) {
        bf16x8 bfr = *(const bf16x8*)((const char*)Bs + (wn*64 + nf*16 + lr)*128 + kb);
        #pragma unroll
        for (int mf = 0; mf < 4; ++mf)
          acc[mf][nf] = __builtin_amdgcn_mfma_f32_16x16x32_bf16(a[mf], bfr, acc[mf][nf], 0, 0, 0);
      }
    }
  }
  #pragma unroll
  for (int mf = 0; mf < 4; ++mf)
    #pragma unroll
    for (int nf = 0; nf < 4; ++nf)
      #pragma unroll
      for (int r = 0; r < 4; ++r) {
        int m = row0 + wm*64 + mf*16 + lk*4 + r;
        int j = col0 + wn*64 + nf*16 + lr;
        mpW[(size_t)m*D_ + j] = acc[mf][nf][r];
      }
}

// K4: 128x128 m97-structure + bijective XCD-chunked swizzle, (256,4).
__global__ __launch_bounds__(256, 4) void k4_fc1(
    const u16* __restrict__ x1bf, const u16* __restrict__ w1T,
    const float* __restrict__ w1, const float* __restrict__ w2,
    const int* __restrict__ order, const float* __restrict__ cosb,
    const float* __restrict__ mpW, const float* __restrict__ peW,
    float* __restrict__ Zp) {
  __shared__ __align__(16) u16 As[128*64];   // 16 KB
  __shared__ __align__(16) u16 Bs[128*64];   // 16 KB
  __shared__ float zred[2*128*4];            // 4 KB
  int tid = threadIdx.x;
  int lane = tid & 63, wid = tid >> 6;
  int wg = (blockIdx.x & 7)*480 + (blockIdx.x >> 3);
  int colb = wg & 3, rowb = wg >> 2;
  int col0 = colb * 128;
  int row0 = rowb * 128;
  int wm = wid >> 1, wn = wid & 1;
  int lr = lane & 15, lk = lane >> 4;
  int srow = lane >> 3;
  int skel = ((lane & 7) ^ srow) << 3;
  float wl[4];
  #pragma unroll
  for (int nf = 0; nf < 4; ++nf)
    wl[nf] = w1[(size_t)1024*D_ + col0 + wn*64 + nf*16 + lr];
  f32x4 acc[4][4];
  #pragma unroll
  for (int mf = 0; mf < 4; ++mf) {
    #pragma unroll
    for (int r = 0; r < 4; ++r) {
      int m = row0 + wm*64 + mf*16 + lk*4 + r;
      int bidx = m / N_;
      int o = order[m];
      float cs = cosb[m];
      #pragma unroll
      for (int nf = 0; nf < 4; ++nf) {
        int jl = col0 + wn*64 + nf*16 + lr;
        acc[mf][nf][r] = mpW[(size_t)bidx*D_ + jl] + peW[o*D_ + jl] + cs*wl[nf];
      }
    }
  }
  for (int k0 = 0; k0 < D_; k0 += 64) {
    __syncthreads();
    #pragma unroll
    for (int i = 0; i < 4; ++i) {
      int rb = wid*32 + i*8;
      gll16(&x1bf[(size_t)(row0 + rb + srow)*D_ + k0 + skel], &As[rb*64]);
      gll16(&w1T [(size_t)(col0 + rb + srow)*D_ + k0 + skel], &Bs[rb*64]);
    }
    __syncthreads();
    #pragma unroll
    for (int kk = 0; kk < 2; ++kk) {
      int kb = (kk*64 + lk*16) ^ ((lr & 7) << 4);
      bf16x8 a[4];
      #pragma unroll
      for (int mf = 0; mf < 4; ++mf)
        a[mf] = *(const bf16x8*)((const char*)As + (wm*64 + mf*16 + lr)*128 + kb);
      #pragma unroll
      for (int nf = 0; nf < 4; ++nf) {
        bf16x8 bfr = *(const bf16x8*)((const char*)Bs + (wn*64 + nf*16 + lr)*128 + kb);
        #pragma unroll
        for (int mf = 0; mf < 4; ++mf)
          acc[mf][nf] = __builtin_amdgcn_mfma_f32_16x16x32_bf16(a[mf], bfr, acc[mf][nf], 0, 0, 0);
      }
    }
  }
  float w2r[4][4];
  #pragma unroll
  for (int nf = 0; nf < 4; ++nf)
    *(float4*)w2r[nf] = *(const float4*)&w2[(col0 + wn*64 + nf*16 + lr)*4];
  #pragma unroll
  for (int mf = 0; mf < 4; ++mf) {
    #pragma unroll
    for (int r = 0; r < 4; ++r) {
      int rowt = wm*64 + mf*16 + lk*4 + r;
      float z0=0.f, z1=0.f, z2=0.f, z3=0.f;
      #pragma unroll
      for (int nf = 0; nf < 4; ++nf) {
        float t = ftanh(acc[mf][nf][r]);
        z0 += t * w2r[nf][0]; z1 += t * w2r[nf][1];
        z2 += t * w2r[nf][2]; z3 += t * w2r[nf][3];
      }
      #pragma unroll
      for (int msk = 1; msk <= 8; msk <<= 1) {
        z0 += __shfl_xor(z0, msk); z1 += __shfl_xor(z1, msk);
        z2 += __shfl_xor(z2, msk); z3 += __shfl_xor(z3, msk);
      }
      if (lr == 0)
        *(float4*)&zred[(wn*128 + rowt)*4] = make_float4(z0, z1, z2, z3);
    }
  }
  __syncthreads();
  if (tid < 128) {
    float4 s0 = *(float4*)&zred[tid*4];
    float4 s1 = *(float4*)&zred[(128 + tid)*4];
    *(float4*)&Zp[((size_t)colb*M_ + row0 + tid)*4] =
        make_float4(s0.x+s1.x, s0.y+s1.y, s0.z+s1.z, s0.w+s1.w);
  }
}

// K5: wave-per-batch. Sums 4 Zp partials; in-wave softmax; bf16x8 pooling
// with explicit load-ahead (prefetch row j+1 + abuf scalars before using j);
// LN2 -> Hh2 bf16 + head-mean f32.
__global__ __launch_bounds__(512) void k5_attn(
    const float* __restrict__ Zp, const float* __restrict__ b2,
    const unsigned char* __restrict__ amask, const u16* __restrict__ x1bf,
    const float* __restrict__ mpx, const float* __restrict__ g2,
    const float* __restrict__ bln2, u16* __restrict__ Hh2bf,
    float* __restrict__ hmean) {
  __shared__ float abuf[8][120];
  int tid = threadIdx.x;
  int wid = tid >> 6, lane = tid & 63;
  int b = blockIdx.x*8 + wid;
  bool act = lane < N_;
  int tok = b*N_ + (act ? lane : 0);
  float zz[4] = {-INFINITY, -INFINITY, -INFINITY, -INFINITY};
  if (act) {
    float4 za = *(const float4*)&Zp[(size_t)tok*4];
    float4 zb = *(const float4*)&Zp[((size_t)M_ + tok)*4];
    float4 zc = *(const float4*)&Zp[((size_t)2*M_ + tok)*4];
    float4 zd = *(const float4*)&Zp[((size_t)3*M_ + tok)*4];
    float4 bv = *(const float4*)b2;
    zz[0] = za.x+zb.x+zc.x+zd.x+bv.x; zz[1] = za.y+zb.y+zc.y+zd.y+bv.y;
    zz[2] = za.z+zb.z+zc.z+zd.z+bv.z; zz[3] = za.w+zb.w+zc.w+zd.w+bv.w;
    if (amask[tok]) { zz[0]=zz[1]=zz[2]=zz[3]=-INFINITY; }
  }
  float p[4];
  #pragma unroll
  for (int h = 0; h < 4; ++h) {
    float mx = wmax(zz[h]);
    float e = act ? __expf(zz[h] - mx) : 0.f;
    float s = wsum(e);
    p[h] = e / s;
  }
  if (act) *(float4*)&abuf[wid][lane*4] = make_float4(p[0], p[1], p[2], p[3]);
  __syncthreads();
  float hv[4][8] = {};
  const u16* xr = &x1bf[(size_t)b*N_*D_ + lane*8];
  // software-pipelined pooling: prefetch row j+1 and its attention scalars
  bf16x8 xb = *(const bf16x8*)xr;
  float a0 = abuf[wid][0*N_], a1 = abuf[wid][1*N_],
        a2 = abuf[wid][2*N_], a3 = abuf[wid][3*N_];
  for (int j = 0; j < N_; ++j) {
    bf16x8 xc = xb;
    float c0 = a0, c1 = a1, c2 = a2, c3 = a3;
    if (j + 1 < N_) {
      xb = *(const bf16x8*)(xr + (size_t)(j+1)*D_);
      a0 = abuf[wid][0*N_ + j+1]; a1 = abuf[wid][1*N_ + j+1];
      a2 = abuf[wid][2*N_ + j+1]; a3 = abuf[wid][3*N_ + j+1];
    }
    float xv[8];
    #pragma unroll
    for (int e = 0; e < 8; ++e) xv[e] = bf2f((u16)xc[e]);
    #pragma unroll
    for (int e = 0; e < 8; ++e) {
      hv[0][e] += c0 * xv[e];
      hv[1][e] += c1 * xv[e];
      hv[2][e] += c2 * xv[e];
      hv[3][e] += c3 * xv[e];
    }
  }
  float mpxv[8];
  *(float4*)&mpxv[0] = *(const float4*)&mpx[(size_t)b*D_ + lane*8];
  *(float4*)&mpxv[4] = *(const float4*)&mpx[(size_t)b*D_ + lane*8 + 4];
  float s1 = 0.f, s2 = 0.f;
  #pragma unroll
  for (int i = 0; i < 4; ++i)
    #pragma unroll
    for (int e = 0; e < 8; ++e) {
      hv[i][e] += mpxv[e];
      s1 += hv[i][e];
      s2 += hv[i][e]*hv[i][e];
    }
  wsum2(s1, s2);
  float mu = s1 * (1.f/2048.f);
  float var = s2 * (1.f/2048.f) - mu*mu;
  float rs = 1.f / sqrtf(var + 1e-5f);
  float hm[8] = {0,0,0,0,0,0,0,0};
  #pragma unroll
  for (int i = 0; i < 4; ++i) {
    int idx = i*D_ + lane*8;
    float gg[8], bb[8];
    *(float4*)&gg[0] = *(const float4*)&g2[idx];
    *(float4*)&gg[4] = *(const float4*)&g2[idx+4];
    *(float4*)&bb[0] = *(const float4*)&bln2[idx];
    *(float4*)&bb[4] = *(const float4*)&bln2[idx+4];
    bf16x8 ob;
    #pragma unroll
    for (int e = 0; e < 8; ++e) {
      float v = gg[e]*((hv[i][e]-mu)*rs) + bb[e];
      hm[e] += v;
      ob[e] = (short)f2bf(v);
    }
    *(bf16x8*)&Hh2bf[(size_t)b*2048 + idx] = ob;
  }
  #pragma unroll
  for (int e = 0; e < 8; ++e) hm[e] *= 0.25f;
  *(float4*)&hmean[(size_t)b*D_ + lane*8]     = *(float4*)&hm[0];
  *(float4*)&hmean[(size_t)b*D_ + lane*8 + 4] = *(float4*)&hm[4];
}

// K6: fc2 GEMM 128x128 tile, BK=64, split-K=4 -> 512 blocks. (256,4).
// Writes bf16 partials (halves write traffic; LN3 downstream absorbs rounding).
__global__ __launch_bounds__(256, 4) void k6_fc2(
    const u16* __restrict__ Hh2bf, const u16* __restrict__ fwT,
    u16* __restrict__ pred_p) {
  __shared__ __align__(16) u16 As[128*64];
  __shared__ __align__(16) u16 Bs[128*64];
  int tid = threadIdx.x;
  int lane = tid & 63, wid = tid >> 6;
  int wg = (blockIdx.x & 7)*64 + (blockIdx.x >> 3);
  int kz = wg >> 7;
  int rem = wg & 127;
  int rowb = rem >> 2, colb = rem & 3;
  int row0 = rowb*128, col0 = colb*128;
  int kbase = kz*512;
  int wm = wid >> 1, wn = wid & 1;
  int lr = lane & 15, lk = lane >> 4;
  int srow = lane >> 3;
  int skel = ((lane & 7) ^ srow) << 3;
  f32x4 acc[4][4] = {};
  for (int k0 = kbase; k0 < kbase + 512; k0 += 64) {
    __syncthreads();
    #pragma unroll
    for (int i = 0; i < 4; ++i) {
      int rb = wid*32 + i*8;
      gll16(&Hh2bf[(size_t)(row0 + rb + srow)*2048 + k0 + skel], &As[rb*64]);
      gll16(&fwT  [(size_t)(col0 + rb + srow)*2048 + k0 + skel], &Bs[rb*64]);
    }
    __syncthreads();
    #pragma unroll
    for (int kk = 0; kk < 2; ++kk) {
      int kb = (kk*64 + lk*16) ^ ((lr & 7) << 4);
      bf16x8 a[4];
      #pragma unroll
      for (int mf = 0; mf < 4; ++mf)
        a[mf] = *(const bf16x8*)((const char*)As + (wm*64 + mf*16 + lr)*128 + kb);
      #pragma unroll
      for (int nf = 0; nf < 4; ++nf) {
        bf16x8 bfr = *(const bf16x8*)((const char*)Bs + (wn*64 + nf*16 + lr)*128 + kb);
        #pragma unroll
        for (int mf = 0; mf < 4; ++mf)
          acc[mf][nf] = __builtin_amdgcn_mfma_f32_16x16x32_bf16(a[mf], bfr, acc[mf][nf], 0, 0, 0);
      }
    }
  }
  u16* dst = pred_p + (size_t)kz * B_ * D_;
  #pragma unroll
  for (int mf = 0; mf < 4; ++mf)
    #pragma unroll
    for (int nf = 0; nf < 4; ++nf)
      #pragma unroll
      for (int r = 0; r < 4; ++r) {
        int m = row0 + wm*64 + mf*16 + lk*4 + r;
        int j = col0 + wn*64 + nf*16 + lr;
        dst[(size_t)m*D_ + j] = f2bf(acc[mf][nf][r]);
      }
}

// K7: wave-per-row. Combine 4 bf16 split-K partials + fb, LN3, + head-mean, LN4.
__global__ __launch_bounds__(512) void k7_final(
    const u16* __restrict__ pred_p, const float* __restrict__ hmean,
    const float* __restrict__ fb,
    const float* __restrict__ g3, const float* __restrict__ b3,
    const float* __restrict__ g4, const float* __restrict__ b4,
    float* __restrict__ out) {
  int tid = threadIdx.x;
  int wid = tid >> 6, lane = tid & 63;
  int b = blockIdx.x*8 + wid;
  int d0 = lane*8;
  size_t i = (size_t)b*D_ + d0;
  size_t BD = (size_t)B_*D_;
  bf16x8 a0 = *(const bf16x8*)&pred_p[i];
  bf16x8 a1 = *(const bf16x8*)&pred_p[BD + i];
  bf16x8 a2 = *(const bf16x8*)&pred_p[2*BD + i];
  bf16x8 a3 = *(const bf16x8*)&pred_p[3*BD + i];
  float fbv[8];
  *(float4*)&fbv[0] = *(const float4*)&fb[d0];
  *(float4*)&fbv[4] = *(const float4*)&fb[d0+4];
  float p[8];
  #pragma unroll
  for (int e = 0; e < 8; ++e)
    p[e] = bf2f((u16)a0[e]) + bf2f((u16)a1[e]) + bf2f((u16)a2[e])
         + bf2f((u16)a3[e]) + fbv[e];
  float s1 = 0.f, s2 = 0.f;
  #pragma unroll
  for (int e = 0; e < 8; ++e) { s1 += p[e]; s2 += p[e]*p[e]; }
  wsum2(s1, s2);
  float mu = s1*(1.f/D_);
  float var = s2*(1.f/D_) - mu*mu;
  float rs = 1.f / sqrtf(var + 1e-5f);
  float g3v[8], b3v[8], hmv[8], q[8];
  *(float4*)&g3v[0] = *(const float4*)&g3[d0];
  *(float4*)&g3v[4] = *(const float4*)&g3[d0+4];
  *(float4*)&b3v[0] = *(const float4*)&b3[d0];
  *(float4*)&b3v[4] = *(const float4*)&b3[d0+4];
  *(float4*)&hmv[0] = *(const float4*)&hmean[i];
  *(float4*)&hmv[4] = *(const float4*)&hmean[i+4];
  float t1 = 0.f, t2 = 0.f;
  #pragma unroll
  for (int e = 0; e < 8; ++e) {
    q[e] = g3v[e]*((p[e]-mu)*rs) + b3v[e] + hmv[e];
    t1 += q[e]; t2 += q[e]*q[e];
  }
  wsum2(t1, t2);
  mu = t1*(1.f/D_);
  var = t2*(1.f/D_) - mu*mu;
  rs = 1.f / sqrtf(var + 1e-5f);
  float g4v[8], b4v[8], o[8];
  *(float4*)&g4v[0] = *(const float4*)&g4[d0];
  *(float4*)&g4v[4] = *(const float4*)&g4[d0+4];
  *(float4*)&b4v[0] = *(const float4*)&b4[d0];
  *(float4*)&b4v[4] = *(const float4*)&b4[d0+4];
  #pragma unroll
  for (int e = 0; e < 8; ++e) o[e] = g4v[e]*((q[e]-mu)*rs) + b4v[e];
  *(float4*)&out[i]   = *(float4*)&o[0];
  *(float4*)&out[i+4] = *(float4*)&o[4];
}

extern "C" void kernel_launch(void* const* d_in, const int* in_sizes, int n_in,
                              void* d_out, int out_size, void* d_ws, size_t ws_size,
                              hipStream_t stream) {
  const float* x      = (const float*)d_in[0];
  const unsigned char* amask = (const unsigned char*)d_in[1];
  const int*   order  = (const int*)d_in[2];
  const float* ndocs  = (const float*)d_in[3];
  const float* dw     = (const float*)d_in[4];
  const float* pe     = (const float*)d_in[6];
  const float* w1     = (const float*)d_in[7];
  const float* b1     = (const float*)d_in[8];
  const float* w2     = (const float*)d_in[9];
  const float* b2     = (const float*)d_in[10];
  const float* fw     = (const float*)d_in[11];
  const float* fb     = (const float*)d_in[12];
  const float* g1     = (const float*)d_in[13];
  const float* bln1   = (const float*)d_in[14];
  const float* g2     = (const float*)d_in[15];
  const float* bln2   = (const float*)d_in[16];
  const float* g3     = (const float*)d_in[17];
  const float* b3     = (const float*)d_in[18];
  const float* g4     = (const float*)d_in[19];
  const float* b4     = (const float*)d_in[20];
  float* out = (float*)d_out;

  char* ws = (char*)d_ws;
  size_t off = 0;
  u16*   x1bf   = (u16*)(ws + off);   off += (size_t)M_*D_*2;        // 125.8 MB
  u16*   mpbf   = (u16*)(ws + off);   off += (size_t)B_*D_*2;        // 4.2 MB
  float* mpx    = (float*)(ws + off); off += (size_t)B_*D_*4;        // 8.4 MB
  float* mpW    = (float*)(ws + off); off += (size_t)B_*D_*4;        // 8.4 MB
  float* hmean  = (float*)(ws + off); off += (size_t)B_*D_*4;        // 8.4 MB
  float* peW    = (float*)(ws + off); off += (size_t)PE_ROWS*D_*4;
  float* cosb   = (float*)(ws + off); off += (size_t)M_*4;
  float* Zp     = (float*)(ws + off); off += (size_t)4*M_*4*4;       // 7.9 MB
  u16*   pred_p = (u16*)(ws + off);   off += (size_t)4*B_*D_*2;      // 16.8 MB
  u16*   Hh2bf  = (u16*)(ws + off);   off += (size_t)B_*2048*2;      // 16.8 MB
  u16*   w1T    = (u16*)(ws + off);   off += (size_t)D_*D_*2;        // 0.5 MB
  u16*   w1mT   = (u16*)(ws + off);   off += (size_t)D_*D_*2;        // 0.5 MB
  u16*   fwT    = (u16*)(ws + off);   off += (size_t)D_*2048*2;      // 2.1 MB
  (void)ws_size; (void)in_sizes; (void)n_in; (void)out_size;

  k1_mega<<<B_ + 384 + PE_ROWS, 512, 0, stream>>>(
      x, order, ndocs, dw, pe, g1, bln1, w1, fw,
      x1bf, mpbf, mpx, cosb, w1T, w1mT, fwT, peW);
  k2_mpw<<<128, 256, 0, stream>>>(mpbf, w1mT, b1, mpW);
  k4_fc1<<<3840, 256, 0, stream>>>(x1bf, w1T, w1, w2, order, cosb,
                                   mpW, peW, Zp);
  k5_attn<<<B_/8, 512, 0, stream>>>(Zp, b2, amask, x1bf, mpx, g2, bln2,
                                    Hh2bf, hmean);
  k6_fc2<<<512, 256, 0, stream>>>(Hh2bf, fwT, pred_p);
  k7_final<<<B_/8, 512, 0, stream>>>(pred_p, hmean, fb, g3, b3, g4, b4, out);
}

// Round 16
// 281.113 us; speedup vs baseline: 1.0133x; 1.0133x over previous
//
#include <hip/hip_runtime.h>
#include <hip/hip_bf16.h>

#define B_ 4096
#define N_ 30
#define D_ 512
#define H_ 4
#define M_ (B_*N_)      // 122880 tokens
#define PE_ROWS 31

typedef unsigned short u16;
typedef __attribute__((ext_vector_type(8))) short bf16x8;
typedef __attribute__((ext_vector_type(4))) float f32x4;

__device__ __forceinline__ float bf2f(u16 s) { return __uint_as_float(((unsigned)s) << 16); }
__device__ __forceinline__ u16 f2bf(float f) {
  __hip_bfloat16 h = __float2bfloat16(f);
  return *reinterpret_cast<u16*>(&h);
}

// fast tanh: 1 - 2/(exp(2x)+1)
__device__ __forceinline__ float ftanh(float x) {
  float e = __expf(2.f * x);
  return 1.f - 2.f * __builtin_amdgcn_rcpf(e + 1.f);
}

// async global->LDS, 16B per lane. LDS dest = wave-uniform base + lane*16.
__device__ __forceinline__ void gll16(const void* g, void* l) {
  __builtin_amdgcn_global_load_lds(
      (const __attribute__((address_space(1))) unsigned int*)g,
      (__attribute__((address_space(3))) unsigned int*)l, 16, 0, 0);
}

// full-wave (64-lane) reductions; interleaved variants run k independent
// trees in ONE 6-round pass (latency ~= single wsum).
__device__ __forceinline__ float wsum(float v) {
  #pragma unroll
  for (int m = 32; m >= 1; m >>= 1) v += __shfl_xor(v, m);
  return v;
}
__device__ __forceinline__ void wsum2(float& a, float& b) {
  #pragma unroll
  for (int m = 32; m >= 1; m >>= 1) {
    a += __shfl_xor(a, m); b += __shfl_xor(b, m);
  }
}
__device__ __forceinline__ void wsum4(float& a, float& b, float& c, float& d) {
  #pragma unroll
  for (int m = 32; m >= 1; m >>= 1) {
    a += __shfl_xor(a, m); b += __shfl_xor(b, m);
    c += __shfl_xor(c, m); d += __shfl_xor(d, m);
  }
}
__device__ __forceinline__ float wmax(float v) {
  #pragma unroll
  for (int m = 32; m >= 1; m >>= 1) v = fmaxf(v, __shfl_xor(v, m));
  return v;
}

// K1 mega: blocks [0,4096) = per-batch prep (paired-token interleaved
// reductions); blocks [4096+) do preamble transposes + peW concurrently.
__global__ __launch_bounds__(512) void k1_mega(
    const float* __restrict__ x, const int* __restrict__ order,
    const float* __restrict__ ndocs, const float* __restrict__ dw,
    const float* __restrict__ pe, const float* __restrict__ g1,
    const float* __restrict__ bln1,
    const float* __restrict__ w1, const float* __restrict__ fw,
    u16* __restrict__ x1bf, u16* __restrict__ mpbf, float* __restrict__ mpx,
    float* __restrict__ cosb,
    u16* __restrict__ w1T, u16* __restrict__ w1mT, u16* __restrict__ fwT,
    float* __restrict__ peW) {
  __shared__ __align__(16) char smem[32896];
  int bid = blockIdx.x;
  int tid = threadIdx.x;
  if (bid >= B_) {
    int r = bid - B_;
    if (r < 384) {
      const float* in; u16* outp; int Kdim, Jdim, bx, by;
      if (r < 64)       { in = w1;            outp = w1T;  Kdim = 512;  Jdim = 512;  bx = r >> 3;        by = r & 7; }
      else if (r < 128) { in = w1 + 512*512;  outp = w1mT; Kdim = 512;  Jdim = 512;  bx = (r-64) >> 3;   by = (r-64) & 7; }
      else              { in = fw;            outp = fwT;  Kdim = 2048; Jdim = 512;  bx = (r-128) >> 3;  by = (r-128) & 7; }
      int k0 = bx*64, j0 = by*64;
      float* tile = (float*)smem;            // [64][65]
      int rowk = tid >> 3, c8 = (tid & 7) * 8;
      float4 v0 = *(const float4*)&in[(size_t)(k0+rowk)*Jdim + j0 + c8];
      float4 v1 = *(const float4*)&in[(size_t)(k0+rowk)*Jdim + j0 + c8 + 4];
      float* tr = tile + rowk*65;
      tr[c8+0]=v0.x; tr[c8+1]=v0.y; tr[c8+2]=v0.z; tr[c8+3]=v0.w;
      tr[c8+4]=v1.x; tr[c8+5]=v1.y; tr[c8+6]=v1.z; tr[c8+7]=v1.w;
      __syncthreads();
      int j = tid >> 3, k8 = (tid & 7) * 8;
      u16 tmp[8];
      #pragma unroll
      for (int i = 0; i < 8; ++i) tmp[i] = f2bf(tile[(k8+i)*65 + j]);
      *(uint4*)&outp[(size_t)(j0+j)*Kdim + k0 + k8] = *(uint4*)tmp;
    } else {
      int p = r - 384;
      float* pes = (float*)smem;
      pes[tid] = pe[(size_t)p*D_ + tid];
      __syncthreads();
      float acc = 0.f;
      for (int dd = 0; dd < D_; ++dd) acc += pes[dd] * w1[(size_t)dd*D_ + tid];
      peW[p*D_ + tid] = acc;
    }
    return;
  }
  // --- k1 path ---
  float* lds_mp  = (float*)smem;
  float* lds_mpx = lds_mp + 8*512;
  float* xps     = lds_mpx + 8*512;
  int b = bid;
  int wid = tid >> 6, lane = tid & 63;
  int d0 = lane * 8;
  float g[8], bl[8];
  *(float4*)&g[0]  = *(const float4*)&g1[d0];
  *(float4*)&g[4]  = *(const float4*)&g1[d0+4];
  *(float4*)&bl[0] = *(const float4*)&bln1[d0];
  *(float4*)&bl[4] = *(const float4*)&bln1[d0+4];
  float xp_reg[4][8];
  float accmp[8] = {0,0,0,0,0,0,0,0}, accmpx[8] = {0,0,0,0,0,0,0,0};
  #pragma unroll
  for (int tp = 0; tp < 2; ++tp) {
    int n0 = wid + 16*tp, n1 = n0 + 8;
    bool a1 = (n1 < N_);                     // wave-uniform
    int tok0 = b*N_ + n0, tok1 = b*N_ + n1;
    float v0[8], v1[8];
    *(float4*)&v0[0] = *(const float4*)&x[(size_t)tok0*D_ + d0];
    *(float4*)&v0[4] = *(const float4*)&x[(size_t)tok0*D_ + d0 + 4];
    int o0 = order[tok0];
    float wv0 = dw[tok0];
    int o1 = 0; float wv1 = 0.f;
    if (a1) {
      *(float4*)&v1[0] = *(const float4*)&x[(size_t)tok1*D_ + d0];
      *(float4*)&v1[4] = *(const float4*)&x[(size_t)tok1*D_ + d0 + 4];
      o1 = order[tok1];
      wv1 = dw[tok1];
    }
    float ss0=0.f, sm0=0.f, ss1=0.f, sm1=0.f;
    #pragma unroll
    for (int i = 0; i < 8; ++i) { ss0 += v0[i]*v0[i]; sm0 += v0[i]; }
    if (a1) {
      #pragma unroll
      for (int i = 0; i < 8; ++i) { ss1 += v1[i]*v1[i]; sm1 += v1[i]; }
    }
    wsum4(ss0, sm0, ss1, sm1);               // 4 chains, one 6-round pass
    // token 0
    float inv0 = 1.f / fmaxf(sqrtf(ss0), 1e-8f);
    float mu0 = sm0 * inv0 * (1.f/D_);
    float rs0 = 1.f / sqrtf(ss0*inv0*inv0*(1.f/D_) - mu0*mu0 + 1e-5f);
    float p80[8];
    *(float4*)&p80[0] = *(const float4*)&pe[(size_t)o0*D_ + d0];
    *(float4*)&p80[4] = *(const float4*)&pe[(size_t)o0*D_ + d0 + 4];
    float sq0 = 0.f, sq1 = 0.f;
    bf16x8 xb0;
    #pragma unroll
    for (int i = 0; i < 8; ++i) {
      float x1v = g[i]*((v0[i]*inv0 - mu0)*rs0) + bl[i];
      xb0[i] = (short)f2bf(x1v);
      float xpv = x1v + p80[i];
      xp_reg[2*tp][i] = xpv;
      accmp[i]  += wv0*xpv;
      accmpx[i] += wv0*x1v;
      sq0 += xpv*xpv;
    }
    *(bf16x8*)&x1bf[(size_t)tok0*D_ + d0] = xb0;
    // token 1 (guarded, wave-uniform)
    if (a1) {
      float inv1 = 1.f / fmaxf(sqrtf(ss1), 1e-8f);
      float mu1 = sm1 * inv1 * (1.f/D_);
      float rs1 = 1.f / sqrtf(ss1*inv1*inv1*(1.f/D_) - mu1*mu1 + 1e-5f);
      float p81[8];
      *(float4*)&p81[0] = *(const float4*)&pe[(size_t)o1*D_ + d0];
      *(float4*)&p81[4] = *(const float4*)&pe[(size_t)o1*D_ + d0 + 4];
      bf16x8 xb1;
      #pragma unroll
      for (int i = 0; i < 8; ++i) {
        float x1v = g[i]*((v1[i]*inv1 - mu1)*rs1) + bl[i];
        xb1[i] = (short)f2bf(x1v);
        float xpv = x1v + p81[i];
        xp_reg[2*tp+1][i] = xpv;
        accmp[i]  += wv1*xpv;
        accmpx[i] += wv1*x1v;
        sq1 += xpv*xpv;
      }
      *(bf16x8*)&x1bf[(size_t)tok1*D_ + d0] = xb1;
    }
    wsum2(sq0, sq1);
    if (lane == 0) {
      xps[n0] = sq0;
      if (a1) xps[n1] = sq1;
    }
  }
  #pragma unroll
  for (int i = 0; i < 8; i += 4) {
    *(float4*)&lds_mp[wid*512 + d0 + i]  = *(float4*)&accmp[i];
    *(float4*)&lds_mpx[wid*512 + d0 + i] = *(float4*)&accmpx[i];
  }
  __syncthreads();
  float invnd = 1.f / ndocs[b];
  float mpv[8] = {0,0,0,0,0,0,0,0}, mpxv[8] = {0,0,0,0,0,0,0,0};
  #pragma unroll
  for (int w = 0; w < 8; ++w) {
    #pragma unroll
    for (int i = 0; i < 8; i += 4) {
      float4 a = *(float4*)&lds_mp[w*512 + d0 + i];
      mpv[i+0] += a.x; mpv[i+1] += a.y; mpv[i+2] += a.z; mpv[i+3] += a.w;
      float4 c = *(float4*)&lds_mpx[w*512 + d0 + i];
      mpxv[i+0] += c.x; mpxv[i+1] += c.y; mpxv[i+2] += c.z; mpxv[i+3] += c.w;
    }
  }
  #pragma unroll
  for (int i = 0; i < 8; ++i) { mpv[i] *= invnd; mpxv[i] *= invnd; }
  if (wid == 0) {
    bf16x8 mb;
    #pragma unroll
    for (int i = 0; i < 8; ++i) mb[i] = (short)f2bf(mpv[i]);
    *(bf16x8*)&mpbf[(size_t)b*D_ + d0] = mb;
  }
  if (wid == 1) {
    #pragma unroll
    for (int i = 0; i < 8; i += 4)
      *(float4*)&mpx[(size_t)b*D_ + d0 + i] = *(float4*)&mpxv[i];
  }
  float mn = 0.f;
  #pragma unroll
  for (int i = 0; i < 8; ++i) mn += mpv[i]*mpv[i];
  float mpn = sqrtf(wsum(mn));
  // phase C: all 4 cosine dots in one interleaved reduce
  float dot[4];
  #pragma unroll
  for (int t = 0; t < 4; ++t) {
    int n = wid + 8*t;
    float dd = 0.f;
    if (n < N_) {
      #pragma unroll
      for (int i = 0; i < 8; ++i) dd += mpv[i]*xp_reg[t][i];
    }
    dot[t] = dd;
  }
  wsum4(dot[0], dot[1], dot[2], dot[3]);
  if (lane == 0) {
    #pragma unroll
    for (int t = 0; t < 4; ++t) {
      int n = wid + 8*t;
      if (n < N_)
        cosb[b*N_ + n] = dot[t] / fmaxf(mpn * sqrtf(xps[n]), 1e-8f);
    }
  }
}

// K2: mpW = mp @ W_mid + b1, MFMA 128x128 tile, BK=64, 128 blocks.
__global__ __launch_bounds__(256, 3) void k2_mpw(
    const u16* __restrict__ mpbf, const u16* __restrict__ w1mT,
    const float* __restrict__ b1, float* __restrict__ mpW) {
  __shared__ __align__(16) u16 As[128*64];
  __shared__ __align__(16) u16 Bs[128*64];
  int tid = threadIdx.x;
  int lane = tid & 63, wid = tid >> 6;
  int wg = (blockIdx.x & 7)*16 + (blockIdx.x >> 3);
  int colb = wg & 3, rowb = wg >> 2;
  int row0 = rowb*128, col0 = colb*128;
  int wm = wid >> 1, wn = wid & 1;
  int lr = lane & 15, lk = lane >> 4;
  int srow = lane >> 3;
  int skel = ((lane & 7) ^ srow) << 3;
  f32x4 acc[4][4];
  #pragma unroll
  for (int nf = 0; nf < 4; ++nf) {
    float bv = b1[col0 + wn*64 + nf*16 + lr];
    #pragma unroll
    for (int mf = 0; mf < 4; ++mf)
      acc[mf][nf] = (f32x4){bv, bv, bv, bv};
  }
  for (int k0 = 0; k0 < D_; k0 += 64) {
    __syncthreads();
    #pragma unroll
    for (int i = 0; i < 4; ++i) {
      int rb = wid*32 + i*8;
      gll16(&mpbf[(size_t)(row0 + rb + srow)*D_ + k0 + skel], &As[rb*64]);
      gll16(&w1mT[(size_t)(col0 + rb + srow)*D_ + k0 + skel], &Bs[rb*64]);
    }
    __syncthreads();
    #pragma unroll
    for (int kk = 0; kk < 2; ++kk) {
      int kb = (kk*64 + lk*16) ^ ((lr & 7) << 4);
      bf16x8 a[4];
      #pragma unroll
      for (int mf = 0; mf < 4; ++mf)
        a[mf] = *(const bf16x8*)((const char*)As + (wm*64 + mf*16 + lr)*128 + kb);
      #pragma unroll
      for (int nf = 0; nf < 4; ++nf) {
        bf16x8 bfr = *(const bf16x8*)((const char*)Bs + (wn*64 + nf*16 + lr)*128 + kb);
        #pragma unroll
        for (int mf = 0; mf < 4; ++mf)
          acc[mf][nf] = __builtin_amdgcn_mfma_f32_16x16x32_bf16(a[mf], bfr, acc[mf][nf], 0, 0, 0);
      }
    }
  }
  #pragma unroll
  for (int mf = 0; mf < 4; ++mf)
    #pragma unroll
    for (int nf = 0; nf < 4; ++nf)
      #pragma unroll
      for (int r = 0; r < 4; ++r) {
        int m = row0 + wm*64 + mf*16 + lk*4 + r;
        int j = col0 + wn*64 + nf*16 + lr;
        mpW[(size_t)m*D_ + j] = acc[mf][nf][r];
      }
}

// K4: 128x128 m97-structure + bijective XCD-chunked swizzle, (256,4).
__global__ __launch_bounds__(256, 4) void k4_fc1(
    const u16* __restrict__ x1bf, const u16* __restrict__ w1T,
    const float* __restrict__ w1, const float* __restrict__ w2,
    const int* __restrict__ order, const float* __restrict__ cosb,
    const float* __restrict__ mpW, const float* __restrict__ peW,
    float* __restrict__ Zp) {
  __shared__ __align__(16) u16 As[128*64];   // 16 KB
  __shared__ __align__(16) u16 Bs[128*64];   // 16 KB
  __shared__ float zred[2*128*4];            // 4 KB
  int tid = threadIdx.x;
  int lane = tid & 63, wid = tid >> 6;
  int wg = (blockIdx.x & 7)*480 + (blockIdx.x >> 3);
  int colb = wg & 3, rowb = wg >> 2;
  int col0 = colb * 128;
  int row0 = rowb * 128;
  int wm = wid >> 1, wn = wid & 1;
  int lr = lane & 15, lk = lane >> 4;
  int srow = lane >> 3;
  int skel = ((lane & 7) ^ srow) << 3;
  float wl[4];
  #pragma unroll
  for (int nf = 0; nf < 4; ++nf)
    wl[nf] = w1[(size_t)1024*D_ + col0 + wn*64 + nf*16 + lr];
  f32x4 acc[4][4];
  #pragma unroll
  for (int mf = 0; mf < 4; ++mf) {
    #pragma unroll
    for (int r = 0; r < 4; ++r) {
      int m = row0 + wm*64 + mf*16 + lk*4 + r;
      int bidx = m / N_;
      int o = order[m];
      float cs = cosb[m];
      #pragma unroll
      for (int nf = 0; nf < 4; ++nf) {
        int jl = col0 + wn*64 + nf*16 + lr;
        acc[mf][nf][r] = mpW[(size_t)bidx*D_ + jl] + peW[o*D_ + jl] + cs*wl[nf];
      }
    }
  }
  for (int k0 = 0; k0 < D_; k0 += 64) {
    __syncthreads();
    #pragma unroll
    for (int i = 0; i < 4; ++i) {
      int rb = wid*32 + i*8;
      gll16(&x1bf[(size_t)(row0 + rb + srow)*D_ + k0 + skel], &As[rb*64]);
      gll16(&w1T [(size_t)(col0 + rb + srow)*D_ + k0 + skel], &Bs[rb*64]);
    }
    __syncthreads();
    #pragma unroll
    for (int kk = 0; kk < 2; ++kk) {
      int kb = (kk*64 + lk*16) ^ ((lr & 7) << 4);
      bf16x8 a[4];
      #pragma unroll
      for (int mf = 0; mf < 4; ++mf)
        a[mf] = *(const bf16x8*)((const char*)As + (wm*64 + mf*16 + lr)*128 + kb);
      #pragma unroll
      for (int nf = 0; nf < 4; ++nf) {
        bf16x8 bfr = *(const bf16x8*)((const char*)Bs + (wn*64 + nf*16 + lr)*128 + kb);
        #pragma unroll
        for (int mf = 0; mf < 4; ++mf)
          acc[mf][nf] = __builtin_amdgcn_mfma_f32_16x16x32_bf16(a[mf], bfr, acc[mf][nf], 0, 0, 0);
      }
    }
  }
  float w2r[4][4];
  #pragma unroll
  for (int nf = 0; nf < 4; ++nf)
    *(float4*)w2r[nf] = *(const float4*)&w2[(col0 + wn*64 + nf*16 + lr)*4];
  #pragma unroll
  for (int mf = 0; mf < 4; ++mf) {
    #pragma unroll
    for (int r = 0; r < 4; ++r) {
      int rowt = wm*64 + mf*16 + lk*4 + r;
      float z0=0.f, z1=0.f, z2=0.f, z3=0.f;
      #pragma unroll
      for (int nf = 0; nf < 4; ++nf) {
        float t = ftanh(acc[mf][nf][r]);
        z0 += t * w2r[nf][0]; z1 += t * w2r[nf][1];
        z2 += t * w2r[nf][2]; z3 += t * w2r[nf][3];
      }
      #pragma unroll
      for (int msk = 1; msk <= 8; msk <<= 1) {
        z0 += __shfl_xor(z0, msk); z1 += __shfl_xor(z1, msk);
        z2 += __shfl_xor(z2, msk); z3 += __shfl_xor(z3, msk);
      }
      if (lr == 0)
        *(float4*)&zred[(wn*128 + rowt)*4] = make_float4(z0, z1, z2, z3);
    }
  }
  __syncthreads();
  if (tid < 128) {
    float4 s0 = *(float4*)&zred[tid*4];
    float4 s1 = *(float4*)&zred[(128 + tid)*4];
    *(float4*)&Zp[((size_t)colb*M_ + row0 + tid)*4] =
        make_float4(s0.x+s1.x, s0.y+s1.y, s0.z+s1.z, s0.w+s1.w);
  }
}

// K5: wave-per-batch. Sums 4 Zp partials; in-wave softmax; bf16x8 pooling;
// LN2 -> Hh2 bf16 + head-mean f32.  (R14 form — load-ahead variant was null.)
__global__ __launch_bounds__(512) void k5_attn(
    const float* __restrict__ Zp, const float* __restrict__ b2,
    const unsigned char* __restrict__ amask, const u16* __restrict__ x1bf,
    const float* __restrict__ mpx, const float* __restrict__ g2,
    const float* __restrict__ bln2, u16* __restrict__ Hh2bf,
    float* __restrict__ hmean) {
  __shared__ float abuf[8][120];
  int tid = threadIdx.x;
  int wid = tid >> 6, lane = tid & 63;
  int b = blockIdx.x*8 + wid;
  bool act = lane < N_;
  int tok = b*N_ + (act ? lane : 0);
  float zz[4] = {-INFINITY, -INFINITY, -INFINITY, -INFINITY};
  if (act) {
    float4 za = *(const float4*)&Zp[(size_t)tok*4];
    float4 zb = *(const float4*)&Zp[((size_t)M_ + tok)*4];
    float4 zc = *(const float4*)&Zp[((size_t)2*M_ + tok)*4];
    float4 zd = *(const float4*)&Zp[((size_t)3*M_ + tok)*4];
    float4 bv = *(const float4*)b2;
    zz[0] = za.x+zb.x+zc.x+zd.x+bv.x; zz[1] = za.y+zb.y+zc.y+zd.y+bv.y;
    zz[2] = za.z+zb.z+zc.z+zd.z+bv.z; zz[3] = za.w+zb.w+zc.w+zd.w+bv.w;
    if (amask[tok]) { zz[0]=zz[1]=zz[2]=zz[3]=-INFINITY; }
  }
  float p[4];
  #pragma unroll
  for (int h = 0; h < 4; ++h) {
    float mx = wmax(zz[h]);
    float e = act ? __expf(zz[h] - mx) : 0.f;
    float s = wsum(e);
    p[h] = e / s;
  }
  if (act) *(float4*)&abuf[wid][lane*4] = make_float4(p[0], p[1], p[2], p[3]);
  __syncthreads();
  float hv[4][8] = {};
  const u16* xr = &x1bf[(size_t)b*N_*D_ + lane*8];
  for (int j = 0; j < N_; ++j) {
    bf16x8 xb = *(const bf16x8*)(xr + (size_t)j*D_);
    float xv[8];
    #pragma unroll
    for (int e = 0; e < 8; ++e) xv[e] = bf2f((u16)xb[e]);
    #pragma unroll
    for (int i = 0; i < 4; ++i) {
      float a = abuf[wid][i*N_ + j];
      #pragma unroll
      for (int e = 0; e < 8; ++e) hv[i][e] += a * xv[e];
    }
  }
  float mpxv[8];
  *(float4*)&mpxv[0] = *(const float4*)&mpx[(size_t)b*D_ + lane*8];
  *(float4*)&mpxv[4] = *(const float4*)&mpx[(size_t)b*D_ + lane*8 + 4];
  float s1 = 0.f, s2 = 0.f;
  #pragma unroll
  for (int i = 0; i < 4; ++i)
    #pragma unroll
    for (int e = 0; e < 8; ++e) {
      hv[i][e] += mpxv[e];
      s1 += hv[i][e];
      s2 += hv[i][e]*hv[i][e];
    }
  wsum2(s1, s2);
  float mu = s1 * (1.f/2048.f);
  float var = s2 * (1.f/2048.f) - mu*mu;
  float rs = 1.f / sqrtf(var + 1e-5f);
  float hm[8] = {0,0,0,0,0,0,0,0};
  #pragma unroll
  for (int i = 0; i < 4; ++i) {
    int idx = i*D_ + lane*8;
    float gg[8], bb[8];
    *(float4*)&gg[0] = *(const float4*)&g2[idx];
    *(float4*)&gg[4] = *(const float4*)&g2[idx+4];
    *(float4*)&bb[0] = *(const float4*)&bln2[idx];
    *(float4*)&bb[4] = *(const float4*)&bln2[idx+4];
    bf16x8 ob;
    #pragma unroll
    for (int e = 0; e < 8; ++e) {
      float v = gg[e]*((hv[i][e]-mu)*rs) + bb[e];
      hm[e] += v;
      ob[e] = (short)f2bf(v);
    }
    *(bf16x8*)&Hh2bf[(size_t)b*2048 + idx] = ob;
  }
  #pragma unroll
  for (int e = 0; e < 8; ++e) hm[e] *= 0.25f;
  *(float4*)&hmean[(size_t)b*D_ + lane*8]     = *(float4*)&hm[0];
  *(float4*)&hmean[(size_t)b*D_ + lane*8 + 4] = *(float4*)&hm[4];
}

// K6: fc2 GEMM 128x128 tile, BK=64, split-K=4 -> 512 blocks. (256,4).
// Writes bf16 partials (halves write traffic; LN3 downstream absorbs rounding).
__global__ __launch_bounds__(256, 4) void k6_fc2(
    const u16* __restrict__ Hh2bf, const u16* __restrict__ fwT,
    u16* __restrict__ pred_p) {
  __shared__ __align__(16) u16 As[128*64];
  __shared__ __align__(16) u16 Bs[128*64];
  int tid = threadIdx.x;
  int lane = tid & 63, wid = tid >> 6;
  int wg = (blockIdx.x & 7)*64 + (blockIdx.x >> 3);
  int kz = wg >> 7;
  int rem = wg & 127;
  int rowb = rem >> 2, colb = rem & 3;
  int row0 = rowb*128, col0 = colb*128;
  int kbase = kz*512;
  int wm = wid >> 1, wn = wid & 1;
  int lr = lane & 15, lk = lane >> 4;
  int srow = lane >> 3;
  int skel = ((lane & 7) ^ srow) << 3;
  f32x4 acc[4][4] = {};
  for (int k0 = kbase; k0 < kbase + 512; k0 += 64) {
    __syncthreads();
    #pragma unroll
    for (int i = 0; i < 4; ++i) {
      int rb = wid*32 + i*8;
      gll16(&Hh2bf[(size_t)(row0 + rb + srow)*2048 + k0 + skel], &As[rb*64]);
      gll16(&fwT  [(size_t)(col0 + rb + srow)*2048 + k0 + skel], &Bs[rb*64]);
    }
    __syncthreads();
    #pragma unroll
    for (int kk = 0; kk < 2; ++kk) {
      int kb = (kk*64 + lk*16) ^ ((lr & 7) << 4);
      bf16x8 a[4];
      #pragma unroll
      for (int mf = 0; mf < 4; ++mf)
        a[mf] = *(const bf16x8*)((const char*)As + (wm*64 + mf*16 + lr)*128 + kb);
      #pragma unroll
      for (int nf = 0; nf < 4; ++nf) {
        bf16x8 bfr = *(const bf16x8*)((const char*)Bs + (wn*64 + nf*16 + lr)*128 + kb);
        #pragma unroll
        for (int mf = 0; mf < 4; ++mf)
          acc[mf][nf] = __builtin_amdgcn_mfma_f32_16x16x32_bf16(a[mf], bfr, acc[mf][nf], 0, 0, 0);
      }
    }
  }
  u16* dst = pred_p + (size_t)kz * B_ * D_;
  #pragma unroll
  for (int mf = 0; mf < 4; ++mf)
    #pragma unroll
    for (int nf = 0; nf < 4; ++nf)
      #pragma unroll
      for (int r = 0; r < 4; ++r) {
        int m = row0 + wm*64 + mf*16 + lk*4 + r;
        int j = col0 + wn*64 + nf*16 + lr;
        dst[(size_t)m*D_ + j] = f2bf(acc[mf][nf][r]);
      }
}

// K7: wave-per-row. Combine 4 bf16 split-K partials + fb, LN3, + head-mean, LN4.
__global__ __launch_bounds__(512) void k7_final(
    const u16* __restrict__ pred_p, const float* __restrict__ hmean,
    const float* __restrict__ fb,
    const float* __restrict__ g3, const float* __restrict__ b3,
    const float* __restrict__ g4, const float* __restrict__ b4,
    float* __restrict__ out) {
  int tid = threadIdx.x;
  int wid = tid >> 6, lane = tid & 63;
  int b = blockIdx.x*8 + wid;
  int d0 = lane*8;
  size_t i = (size_t)b*D_ + d0;
  size_t BD = (size_t)B_*D_;
  bf16x8 a0 = *(const bf16x8*)&pred_p[i];
  bf16x8 a1 = *(const bf16x8*)&pred_p[BD + i];
  bf16x8 a2 = *(const bf16x8*)&pred_p[2*BD + i];
  bf16x8 a3 = *(const bf16x8*)&pred_p[3*BD + i];
  float fbv[8];
  *(float4*)&fbv[0] = *(const float4*)&fb[d0];
  *(float4*)&fbv[4] = *(const float4*)&fb[d0+4];
  float p[8];
  #pragma unroll
  for (int e = 0; e < 8; ++e)
    p[e] = bf2f((u16)a0[e]) + bf2f((u16)a1[e]) + bf2f((u16)a2[e])
         + bf2f((u16)a3[e]) + fbv[e];
  float s1 = 0.f, s2 = 0.f;
  #pragma unroll
  for (int e = 0; e < 8; ++e) { s1 += p[e]; s2 += p[e]*p[e]; }
  wsum2(s1, s2);
  float mu = s1*(1.f/D_);
  float var = s2*(1.f/D_) - mu*mu;
  float rs = 1.f / sqrtf(var + 1e-5f);
  float g3v[8], b3v[8], hmv[8], q[8];
  *(float4*)&g3v[0] = *(const float4*)&g3[d0];
  *(float4*)&g3v[4] = *(const float4*)&g3[d0+4];
  *(float4*)&b3v[0] = *(const float4*)&b3[d0];
  *(float4*)&b3v[4] = *(const float4*)&b3[d0+4];
  *(float4*)&hmv[0] = *(const float4*)&hmean[i];
  *(float4*)&hmv[4] = *(const float4*)&hmean[i+4];
  float t1 = 0.f, t2 = 0.f;
  #pragma unroll
  for (int e = 0; e < 8; ++e) {
    q[e] = g3v[e]*((p[e]-mu)*rs) + b3v[e] + hmv[e];
    t1 += q[e]; t2 += q[e]*q[e];
  }
  wsum2(t1, t2);
  mu = t1*(1.f/D_);
  var = t2*(1.f/D_) - mu*mu;
  rs = 1.f / sqrtf(var + 1e-5f);
  float g4v[8], b4v[8], o[8];
  *(float4*)&g4v[0] = *(const float4*)&g4[d0];
  *(float4*)&g4v[4] = *(const float4*)&g4[d0+4];
  *(float4*)&b4v[0] = *(const float4*)&b4[d0];
  *(float4*)&b4v[4] = *(const float4*)&b4[d0+4];
  #pragma unroll
  for (int e = 0; e < 8; ++e) o[e] = g4v[e]*((q[e]-mu)*rs) + b4v[e];
  *(float4*)&out[i]   = *(float4*)&o[0];
  *(float4*)&out[i+4] = *(float4*)&o[4];
}

extern "C" void kernel_launch(void* const* d_in, const int* in_sizes, int n_in,
                              void* d_out, int out_size, void* d_ws, size_t ws_size,
                              hipStream_t stream) {
  const float* x      = (const float*)d_in[0];
  const unsigned char* amask = (const unsigned char*)d_in[1];
  const int*   order  = (const int*)d_in[2];
  const float* ndocs  = (const float*)d_in[3];
  const float* dw     = (const float*)d_in[4];
  const float* pe     = (const float*)d_in[6];
  const float* w1     = (const float*)d_in[7];
  const float* b1     = (const float*)d_in[8];
  const float* w2     = (const float*)d_in[9];
  const float* b2     = (const float*)d_in[10];
  const float* fw     = (const float*)d_in[11];
  const float* fb     = (const float*)d_in[12];
  const float* g1     = (const float*)d_in[13];
  const float* bln1   = (const float*)d_in[14];
  const float* g2     = (const float*)d_in[15];
  const float* bln2   = (const float*)d_in[16];
  const float* g3     = (const float*)d_in[17];
  const float* b3     = (const float*)d_in[18];
  const float* g4     = (const float*)d_in[19];
  const float* b4     = (const float*)d_in[20];
  float* out = (float*)d_out;

  char* ws = (char*)d_ws;
  size_t off = 0;
  u16*   x1bf   = (u16*)(ws + off);   off += (size_t)M_*D_*2;        // 125.8 MB
  u16*   mpbf   = (u16*)(ws + off);   off += (size_t)B_*D_*2;        // 4.2 MB
  float* mpx    = (float*)(ws + off); off += (size_t)B_*D_*4;        // 8.4 MB
  float* mpW    = (float*)(ws + off); off += (size_t)B_*D_*4;        // 8.4 MB
  float* hmean  = (float*)(ws + off); off += (size_t)B_*D_*4;        // 8.4 MB
  float* peW    = (float*)(ws + off); off += (size_t)PE_ROWS*D_*4;
  float* cosb   = (float*)(ws + off); off += (size_t)M_*4;
  float* Zp     = (float*)(ws + off); off += (size_t)4*M_*4*4;       // 7.9 MB
  u16*   pred_p = (u16*)(ws + off);   off += (size_t)4*B_*D_*2;      // 16.8 MB
  u16*   Hh2bf  = (u16*)(ws + off);   off += (size_t)B_*2048*2;      // 16.8 MB
  u16*   w1T    = (u16*)(ws + off);   off += (size_t)D_*D_*2;        // 0.5 MB
  u16*   w1mT   = (u16*)(ws + off);   off += (size_t)D_*D_*2;        // 0.5 MB
  u16*   fwT    = (u16*)(ws + off);   off += (size_t)D_*2048*2;      // 2.1 MB
  (void)ws_size; (void)in_sizes; (void)n_in; (void)out_size;

  k1_mega<<<B_ + 384 + PE_ROWS, 512, 0, stream>>>(
      x, order, ndocs, dw, pe, g1, bln1, w1, fw,
      x1bf, mpbf, mpx, cosb, w1T, w1mT, fwT, peW);
  k2_mpw<<<128, 256, 0, stream>>>(mpbf, w1mT, b1, mpW);
  k4_fc1<<<3840, 256, 0, stream>>>(x1bf, w1T, w1, w2, order, cosb,
                                   mpW, peW, Zp);
  k5_attn<<<B_/8, 512, 0, stream>>>(Zp, b2, amask, x1bf, mpx, g2, bln2,
                                    Hh2bf, hmean);
  k6_fc2<<<512, 256, 0, stream>>>(Hh2bf, fwT, pred_p);
  k7_final<<<B_/8, 512, 0, stream>>>(pred_p, hmean, fb, g3, b3, g4, b4, out);
}